// Round 8
// baseline (190.836 us; speedup 1.0000x reference)
//
#include <hip/hip_runtime.h>

#define BATCH   8
#define LENGTH  4096
#define IN_DIM  512
#define STATE   256
#define OUT_DIM 512
#define NC      256
#define LC      16

typedef __attribute__((ext_vector_type(8))) short bf16x8;
typedef __attribute__((ext_vector_type(4))) float f32x4;

union FragU { bf16x8 v; unsigned u[4]; };

__device__ __forceinline__ unsigned short bf16_rne(float v) {
    unsigned u = __builtin_bit_cast(unsigned, v);
    unsigned r = (u + 0x7FFFu + ((u >> 16) & 1u)) >> 16;
    return (unsigned short)r;
}
__device__ __forceinline__ float bf16_f(unsigned short h) {
    unsigned u = ((unsigned)h) << 16;
    return __builtin_bit_cast(float, u);
}

// ---------------------------------------------------------------------------
// Weight split+transpose, B only (GEMM1's prerequisite): B[512][256] fp32 ->
// hi/lo bf16 planes [STATE][IN_DIM] (RNE). C's split is fused into
// scan_combined (it is only needed by GEMM2).
// ---------------------------------------------------------------------------
__global__ __launch_bounds__(256) void split_B(
    const float* __restrict__ B,
    unsigned short* __restrict__ Bhi, unsigned short* __restrict__ Blo)
{
    int id = blockIdx.x * 256 + threadIdx.x;
    int k = id & (IN_DIM - 1), n = id >> 9;      // Bt[n=state][k=in]
    float v = B[(size_t)k * STATE + n];
    unsigned short h = bf16_rne(v);
    Bhi[id] = h;
    Blo[id] = bf16_rne(v - bf16_f(h));
}

// ---------------------------------------------------------------------------
// GEMM1 + fused scan phase A (byte-identical to round 6, verified).
// Split-bf16 MFMA GEMM, A read as fp32 (in-register hi/lo split).
// Tile 128x128, BK=32, 8 waves (4Mx2N), LDS 2x32KB dbuf, vmcnt(4) prefetch.
// Epilogue: C-write + per-16-row-chunk carry via 4 weighted FMAs + shfl_xor.
// ---------------------------------------------------------------------------
__global__ __launch_bounds__(512, 4) void gemm_dbuf(
    const float* __restrict__ Af, const unsigned short* __restrict__ Bthi,
    const unsigned short* __restrict__ Btlo, float* __restrict__ Cc,
    const float* __restrict__ Av, float* __restrict__ carry,
    int N_, int K)
{
    __shared__ unsigned short lds[2 * 16384];   // 64 KB

    const int tid  = threadIdx.x;
    const int wave = tid >> 6;
    const int lane = tid & 63;
    const int n0 = blockIdx.x * 128;
    const int m0 = blockIdx.y * 128;

    const char* gp[4];
    int ldsoff[4], gstep[4];
    #pragma unroll
    for (int t = 0; t < 4; ++t) {
        int gi = wave * 4 + t;
        if (gi < 16) {          // A plane: 16 KB
            int p = gi * 64 + lane;
            int row = p >> 3, s = p & 7;
            int l = s ^ (row & 7);
            gp[t] = (const char*)(Af + (size_t)(m0 + row) * K + l * 4);
            gstep[t] = 32 * 4;
            ldsoff[t] = gi * 512;
        } else {                // B planes: 8 KB each
            int q2 = (gi - 16) >> 3;
            int pi = gi & 7;
            int p = pi * 64 + lane;
            int row = p >> 2, s = p & 3;
            int l = s ^ ((row >> 1) & 3);
            const unsigned short* base = q2 ? Btlo : Bthi;
            gp[t] = (const char*)(base + (size_t)(n0 + row) * K + l * 8);
            gstep[t] = 32 * 2;
            ldsoff[t] = 8192 + q2 * 4096 + pi * 512;
        }
    }

    const int r = lane & 15, q = lane >> 4;
    const int wm = (wave >> 1) * 32, wn = (wave & 1) * 64;

    int aoff[2][2], boff[4];
    #pragma unroll
    for (int i = 0; i < 2; ++i) {
        int row = wm + i * 16 + r;
        #pragma unroll
        for (int h = 0; h < 2; ++h)
            aoff[i][h] = row * 64 + ((2 * q + h) ^ (row & 7)) * 8;
    }
    #pragma unroll
    for (int j = 0; j < 4; ++j) {
        int row = wn + j * 16 + r;
        boff[j] = row * 32 + (q ^ ((row >> 1) & 3)) * 8;
    }

    f32x4 acc[2][4];
    #pragma unroll
    for (int i = 0; i < 2; ++i)
        #pragma unroll
        for (int j = 0; j < 4; ++j)
            acc[i][j] = (f32x4){0.f, 0.f, 0.f, 0.f};

    #pragma unroll
    for (int t = 0; t < 4; ++t) {
        __builtin_amdgcn_global_load_lds(
            (const __attribute__((address_space(1))) unsigned*)(gp[t]),
            (__attribute__((address_space(3))) unsigned*)(&lds[ldsoff[t]]),
            16, 0, 0);
        gp[t] += gstep[t];
    }

    const int nit = K >> 5;
    for (int it = 0; it < nit; ++it) {
        asm volatile("" ::: "memory");
        __builtin_amdgcn_s_barrier();
        asm volatile("" ::: "memory");
        if (it + 1 < nit) {
            const int bb = ((it + 1) & 1) * 16384;
            #pragma unroll
            for (int t = 0; t < 4; ++t) {
                __builtin_amdgcn_global_load_lds(
                    (const __attribute__((address_space(1))) unsigned*)(gp[t]),
                    (__attribute__((address_space(3))) unsigned*)(&lds[bb + ldsoff[t]]),
                    16, 0, 0);
                gp[t] += gstep[t];
            }
            __builtin_amdgcn_s_waitcnt(0x0F74);   // vmcnt(4)
        } else {
            __builtin_amdgcn_s_waitcnt(0x0F70);   // vmcnt(0)
        }
        asm volatile("" ::: "memory");
        __builtin_amdgcn_s_barrier();
        asm volatile("" ::: "memory");

        const unsigned short* buf = &lds[(it & 1) * 16384];

        FragU ahi[2], alo[2];
        #pragma unroll
        for (int i = 0; i < 2; ++i) {
            #pragma unroll
            for (int h = 0; h < 2; ++h) {
                float4 f = *(const float4*)(buf + aoff[i][h]);
                unsigned bx = __builtin_bit_cast(unsigned, f.x);
                unsigned by = __builtin_bit_cast(unsigned, f.y);
                unsigned bz = __builtin_bit_cast(unsigned, f.z);
                unsigned bw = __builtin_bit_cast(unsigned, f.w);
                ahi[i].u[h * 2]     = __builtin_amdgcn_perm(by, bx, 0x07060302);
                ahi[i].u[h * 2 + 1] = __builtin_amdgcn_perm(bw, bz, 0x07060302);
                float lx = f.x - __builtin_bit_cast(float, bx & 0xFFFF0000u);
                float ly = f.y - __builtin_bit_cast(float, by & 0xFFFF0000u);
                float lz = f.z - __builtin_bit_cast(float, bz & 0xFFFF0000u);
                float lw = f.w - __builtin_bit_cast(float, bw & 0xFFFF0000u);
                alo[i].u[h * 2]     = __builtin_amdgcn_perm(
                    __builtin_bit_cast(unsigned, ly), __builtin_bit_cast(unsigned, lx), 0x07060302);
                alo[i].u[h * 2 + 1] = __builtin_amdgcn_perm(
                    __builtin_bit_cast(unsigned, lw), __builtin_bit_cast(unsigned, lz), 0x07060302);
            }
        }
        FragU bhi[4], blo[4];
        #pragma unroll
        for (int j = 0; j < 4; ++j) {
            bhi[j].v = *(const bf16x8*)(buf +  8192 + boff[j]);
            blo[j].v = *(const bf16x8*)(buf + 12288 + boff[j]);
        }
        #pragma unroll
        for (int i = 0; i < 2; ++i)
            #pragma unroll
            for (int j = 0; j < 4; ++j) {
                acc[i][j] = __builtin_amdgcn_mfma_f32_16x16x32_bf16(ahi[i].v, bhi[j].v, acc[i][j], 0, 0, 0);
                acc[i][j] = __builtin_amdgcn_mfma_f32_16x16x32_bf16(alo[i].v, bhi[j].v, acc[i][j], 0, 0, 0);
                acc[i][j] = __builtin_amdgcn_mfma_f32_16x16x32_bf16(ahi[i].v, blo[j].v, acc[i][j], 0, 0, 0);
            }
    }

    #pragma unroll
    for (int i = 0; i < 2; ++i) {
        #pragma unroll
        for (int reg = 0; reg < 4; ++reg) {
            int mg = m0 + wm + i * 16 + q * 4 + reg;
            float* dst = Cc + (size_t)mg * N_ + n0 + wn + r;
            dst[0]  = acc[i][0][reg];
            dst[16] = acc[i][1][reg];
            dst[32] = acc[i][2][reg];
            dst[48] = acc[i][3][reg];
        }
    }

    // fused scan phase A: carry[b][c][n] = sum_{row} a^(15-row) uB[row][n]
    {
        const int b  = m0 >> 12;
        const int c0 = ((m0 & 4095) + wm) >> 4;
        #pragma unroll
        for (int j = 0; j < 4; ++j) {
            const int n = n0 + wn + j * 16 + r;
            const float a  = Av[n];
            const float a2 = a * a, a3 = a2 * a, a4 = a2 * a2;
            const float a8 = a4 * a4, a12 = a8 * a4;
            const float base = (q == 0) ? a12 : (q == 1) ? a8 : (q == 2) ? a4 : 1.f;
            #pragma unroll
            for (int i = 0; i < 2; ++i) {
                float partial = base * (a3 * acc[i][j][0] + a2 * acc[i][j][1]
                                      + a  * acc[i][j][2] +      acc[i][j][3]);
                partial += __shfl_xor(partial, 16);
                partial += __shfl_xor(partial, 32);
                if (q == 0)
                    carry[((size_t)b * NC + (c0 + i)) * STATE + n] = partial;
            }
        }
    }
}

// ---------------------------------------------------------------------------
// scan_combined: merges round-6's scan_gc + scan_fix into ONE kernel, plus
// the C-weight split (C planes are only needed by GEMM2, which runs after).
// Grid (BATCH, 16) x 256 thr. Block (b,g) recomputes the preceding groups'
// GCs inline from carry (16 independent loads + the SAME 16-fma chain per
// group, then the SAME fmaf(aG,S,gc) combine -> bit-identical association
// to the two-kernel version). Extra carry reads are L2-hot (~30 MB total).
// ---------------------------------------------------------------------------
__global__ __launch_bounds__(256) void scan_combined(
    const float* __restrict__ carry, const float* __restrict__ A,
    const float* __restrict__ x0, const float* __restrict__ C,
    float* __restrict__ entry, float* __restrict__ x_last,
    unsigned short* __restrict__ Chi, unsigned short* __restrict__ Clo)
{
    const int b = blockIdx.x, g = blockIdx.y, n = threadIdx.x;

    // --- fused C split+transpose: 131072 elems over 32768 threads = 4 each ---
    {
        int idx = (b * 16 + g) * 256 + n;
        #pragma unroll
        for (int e = 0; e < 4; ++e) {
            int id2 = idx + e * 32768;
            int k = id2 & (STATE - 1), nn = id2 >> 8;   // Ct[n=out][k=state]
            float v = C[(size_t)k * OUT_DIM + nn];
            unsigned short h = bf16_rne(v);
            Chi[id2] = h;
            Clo[id2] = bf16_rne(v - bf16_f(h));
        }
    }

    const float a = A[n];
    float aL = a;
    #pragma unroll
    for (int k = 0; k < 4; ++k) aL *= aL;     // a^16 = a^LC
    float aG = aL;
    #pragma unroll
    for (int k = 0; k < 4; ++k) aG *= aG;     // a^256 (one group)

    // group-entry S: inline GC of each preceding group (16 independent loads,
    // 16-fma chain), then combine -- identical arithmetic to scan_gc+scan_fix.
    float S = x0[(size_t)b * STATE + n];
    for (int gp = 0; gp < g; ++gp) {
        const float* crp = carry + ((size_t)b * NC + gp * 16) * STATE + n;
        float v[16];
        #pragma unroll
        for (int i = 0; i < 16; ++i) v[i] = crp[(size_t)i * STATE];
        float gc = 0.f;
        #pragma unroll
        for (int i = 0; i < 16; ++i) gc = fmaf(aL, gc, v[i]);
        S = fmaf(aG, S, gc);
    }

    // own group: write entries, step through 16 carries
    const float* cr = carry + ((size_t)b * NC + g * 16) * STATE + n;
    float v[16];
    #pragma unroll
    for (int i = 0; i < 16; ++i) v[i] = cr[(size_t)i * STATE];

    float* en = entry + ((size_t)b * NC + g * 16) * STATE + n;
    float s = S;
    #pragma unroll
    for (int i = 0; i < 16; ++i) {
        en[(size_t)i * STATE] = s;
        s = fmaf(aL, s, v[i]);
    }
    if (g == 15) x_last[(size_t)b * STATE + n] = s;
}

// ---------------------------------------------------------------------------
// GEMM2 + fused scan phase C (byte-identical to round 6, verified).
// Stages fp32 uB like GEMM1 stages u; between staging barrier and fragment
// reads, 256 threads run the 16-step recurrence in place in LDS (seeded from
// entry), then the in-register fp32->hi/lo split feeds the MFMAs.
// ---------------------------------------------------------------------------
__global__ __launch_bounds__(512, 4) void gemm_scan_apply(
    const float* __restrict__ uB, const unsigned short* __restrict__ Bthi,
    const unsigned short* __restrict__ Btlo, const float* __restrict__ Av,
    const float* __restrict__ entry, float* __restrict__ Cc,
    int N_, int K)
{
    __shared__ unsigned short lds[2 * 16384];   // 64 KB

    const int tid  = threadIdx.x;
    const int wave = tid >> 6;
    const int lane = tid & 63;
    const int n0 = blockIdx.x * 128;
    const int m0 = blockIdx.y * 128;
    const int bb_ = m0 >> 12;               // batch
    const int c0_ = (m0 & 4095) >> 4;       // first chunk of this m-band

    const char* gp[4];
    int ldsoff[4], gstep[4];
    #pragma unroll
    for (int t = 0; t < 4; ++t) {
        int gi = wave * 4 + t;
        if (gi < 16) {          // uB fp32 plane: 16 KB
            int p = gi * 64 + lane;
            int row = p >> 3, s = p & 7;
            int l = s ^ (row & 7);
            gp[t] = (const char*)(uB + (size_t)(m0 + row) * K + l * 4);
            gstep[t] = 32 * 4;
            ldsoff[t] = gi * 512;
        } else {                // Ct hi/lo planes: 8 KB each
            int q2 = (gi - 16) >> 3;
            int pi = gi & 7;
            int p = pi * 64 + lane;
            int row = p >> 2, s = p & 3;
            int l = s ^ ((row >> 1) & 3);
            const unsigned short* base = q2 ? Btlo : Bthi;
            gp[t] = (const char*)(base + (size_t)(n0 + row) * K + l * 8);
            gstep[t] = 32 * 2;
            ldsoff[t] = 8192 + q2 * 4096 + pi * 512;
        }
    }

    const int r = lane & 15, q = lane >> 4;
    const int wm = (wave >> 1) * 32, wn = (wave & 1) * 64;

    int aoff[2][2], boff[4];
    #pragma unroll
    for (int i = 0; i < 2; ++i) {
        int row = wm + i * 16 + r;
        #pragma unroll
        for (int h = 0; h < 2; ++h)
            aoff[i][h] = row * 64 + ((2 * q + h) ^ (row & 7)) * 8;
    }
    #pragma unroll
    for (int j = 0; j < 4; ++j) {
        int row = wn + j * 16 + r;
        boff[j] = row * 32 + (q ^ ((row >> 1) & 3)) * 8;
    }

    const int sc = tid >> 5;                // 0..15 (only <8 used)
    const int sk = tid & 31;

    f32x4 acc[2][4];
    #pragma unroll
    for (int i = 0; i < 2; ++i)
        #pragma unroll
        for (int j = 0; j < 4; ++j)
            acc[i][j] = (f32x4){0.f, 0.f, 0.f, 0.f};

    #pragma unroll
    for (int t = 0; t < 4; ++t) {
        __builtin_amdgcn_global_load_lds(
            (const __attribute__((address_space(1))) unsigned*)(gp[t]),
            (__attribute__((address_space(3))) unsigned*)(&lds[ldsoff[t]]),
            16, 0, 0);
        gp[t] += gstep[t];
    }

    const int nit = K >> 5;   // 8
    for (int it = 0; it < nit; ++it) {
        asm volatile("" ::: "memory");
        __builtin_amdgcn_s_barrier();
        asm volatile("" ::: "memory");
        if (it + 1 < nit) {
            const int bb = ((it + 1) & 1) * 16384;
            #pragma unroll
            for (int t = 0; t < 4; ++t) {
                __builtin_amdgcn_global_load_lds(
                    (const __attribute__((address_space(1))) unsigned*)(gp[t]),
                    (__attribute__((address_space(3))) unsigned*)(&lds[bb + ldsoff[t]]),
                    16, 0, 0);
                gp[t] += gstep[t];
            }
            __builtin_amdgcn_s_waitcnt(0x0F74);   // vmcnt(4)
        } else {
            __builtin_amdgcn_s_waitcnt(0x0F70);   // vmcnt(0)
        }
        asm volatile("" ::: "memory");
        __builtin_amdgcn_s_barrier();
        asm volatile("" ::: "memory");

        unsigned short* bufw = &lds[(it & 1) * 16384];
        const unsigned short* buf = bufw;

        // ---- fused scan phase C: uB tile -> x tile, in place (fp32) ----
        if (tid < 256) {
            const int kg = it * 32 + sk;
            const float a = Av[kg];
            float s = entry[((size_t)bb_ * NC + (c0_ + sc)) * STATE + kg];
            #pragma unroll
            for (int j = 0; j < 16; ++j) {
                int row = sc * 16 + j;
                int off = row * 64 + (((sk >> 2) ^ (row & 7)) * 8) + ((sk & 3) * 2);
                float v = *(const float*)(bufw + off);
                s = fmaf(a, s, v);
                *(float*)(bufw + off) = s;
            }
        }
        asm volatile("s_waitcnt lgkmcnt(0)" ::: "memory");
        __builtin_amdgcn_s_barrier();
        asm volatile("" ::: "memory");

        // ---- MFMA path: in-register fp32 -> hi/lo split on x ----
        FragU ahi[2], alo[2];
        #pragma unroll
        for (int i = 0; i < 2; ++i) {
            #pragma unroll
            for (int h = 0; h < 2; ++h) {
                float4 f = *(const float4*)(buf + aoff[i][h]);
                unsigned bx = __builtin_bit_cast(unsigned, f.x);
                unsigned by = __builtin_bit_cast(unsigned, f.y);
                unsigned bz = __builtin_bit_cast(unsigned, f.z);
                unsigned bw = __builtin_bit_cast(unsigned, f.w);
                ahi[i].u[h * 2]     = __builtin_amdgcn_perm(by, bx, 0x07060302);
                ahi[i].u[h * 2 + 1] = __builtin_amdgcn_perm(bw, bz, 0x07060302);
                float lx = f.x - __builtin_bit_cast(float, bx & 0xFFFF0000u);
                float ly = f.y - __builtin_bit_cast(float, by & 0xFFFF0000u);
                float lz = f.z - __builtin_bit_cast(float, bz & 0xFFFF0000u);
                float lw = f.w - __builtin_bit_cast(float, bw & 0xFFFF0000u);
                alo[i].u[h * 2]     = __builtin_amdgcn_perm(
                    __builtin_bit_cast(unsigned, ly), __builtin_bit_cast(unsigned, lx), 0x07060302);
                alo[i].u[h * 2 + 1] = __builtin_amdgcn_perm(
                    __builtin_bit_cast(unsigned, lw), __builtin_bit_cast(unsigned, lz), 0x07060302);
            }
        }
        FragU bhi[4], blo[4];
        #pragma unroll
        for (int j = 0; j < 4; ++j) {
            bhi[j].v = *(const bf16x8*)(buf +  8192 + boff[j]);
            blo[j].v = *(const bf16x8*)(buf + 12288 + boff[j]);
        }
        #pragma unroll
        for (int i = 0; i < 2; ++i)
            #pragma unroll
            for (int j = 0; j < 4; ++j) {
                acc[i][j] = __builtin_amdgcn_mfma_f32_16x16x32_bf16(ahi[i].v, bhi[j].v, acc[i][j], 0, 0, 0);
                acc[i][j] = __builtin_amdgcn_mfma_f32_16x16x32_bf16(alo[i].v, bhi[j].v, acc[i][j], 0, 0, 0);
                acc[i][j] = __builtin_amdgcn_mfma_f32_16x16x32_bf16(ahi[i].v, blo[j].v, acc[i][j], 0, 0, 0);
            }
    }

    #pragma unroll
    for (int i = 0; i < 2; ++i) {
        #pragma unroll
        for (int reg = 0; reg < 4; ++reg) {
            int mg = m0 + wm + i * 16 + q * 4 + reg;
            float* dst = Cc + (size_t)mg * N_ + n0 + wn + r;
            dst[0]  = acc[i][0][reg];
            dst[16] = acc[i][1][reg];
            dst[32] = acc[i][2][reg];
            dst[48] = acc[i][3][reg];
        }
    }
}

// ---------------------------------------------------------------------------
extern "C" void kernel_launch(void* const* d_in, const int* in_sizes, int n_in,
                              void* d_out, int out_size, void* d_ws, size_t ws_size,
                              hipStream_t stream)
{
    const float* u  = (const float*)d_in[0];   // [8,4096,512]
    const float* x0 = (const float*)d_in[1];   // [8,256]
    const float* A  = (const float*)d_in[2];   // [256]
    const float* B  = (const float*)d_in[3];   // [512,256]
    const float* C  = (const float*)d_in[4];   // [256,512]

    const size_t MB = 1024 * 1024;
    char* ws = (char*)d_ws;

    float* uB    = (float*)(ws);                // [M,256] fp32, 32 MB
    float* carry = (float*)(ws + 32 * MB);      // [8,256,256] fp32, 2 MB
    float* entry = (float*)(ws + 34 * MB);      // [8,256,256] fp32, 2 MB
    unsigned short* Bt_hi = (unsigned short*)(ws + 36 * MB);                // 256 KB
    unsigned short* Bt_lo = (unsigned short*)(ws + 36 * MB + 256 * 1024);   // 256 KB
    unsigned short* Ct_hi = (unsigned short*)(ws + 36 * MB + 512 * 1024);   // 256 KB
    unsigned short* Ct_lo = (unsigned short*)(ws + 36 * MB + 768 * 1024);   // 256 KB

    float* y      = (float*)d_out;                             // [8,4096,512] = 64 MB
    float* x_last = y + (size_t)BATCH * LENGTH * OUT_DIM;      // [8,256]

    const int M = BATCH * LENGTH;   // 32768

    // 1. split B weights only (C's split is fused into scan_combined)
    split_B<<<dim3((IN_DIM * STATE) / 256), dim3(256), 0, stream>>>(B, Bt_hi, Bt_lo);

    // 2. GEMM1 (+fused scan phase A): uB = u @ B, carry per 16-row chunk
    gemm_dbuf<<<dim3(STATE / 128, M / 128), dim3(512), 0, stream>>>(
        u, Bt_hi, Bt_lo, uB, A, carry, STATE, IN_DIM);

    // 3. merged entry scan (+C split +x_last), one kernel
    scan_combined<<<dim3(BATCH, 16), dim3(256), 0, stream>>>(
        carry, A, x0, C, entry, x_last, Ct_hi, Ct_lo);

    // 4. GEMM2 (+fused scan phase C): y = scan(uB) @ C
    gemm_scan_apply<<<dim3(OUT_DIM / 128, M / 128), dim3(512), 0, stream>>>(
        uB, Ct_hi, Ct_lo, A, entry, y, OUT_DIM, STATE);
}